// Round 8
// baseline (616.395 us; speedup 1.0000x reference)
//
#include <hip/hip_runtime.h>
#include <stdint.h>

// Problem constants (fixed shapes)
#define BB 4
#define TT 4096
#define DD 1024
#define HH 1024
#define MM (BB * TT)      // 16384
#define NC 128            // scan chunks
#define CL (TT / NC)      // 32 steps per chunk

typedef __bf16 bf16x8 __attribute__((ext_vector_type(8)));
typedef short  s16x8  __attribute__((ext_vector_type(8)));
typedef float  f32x4  __attribute__((ext_vector_type(4)));
typedef float  f32x16 __attribute__((ext_vector_type(16)));

// ---------------- helpers ----------------

__device__ __forceinline__ unsigned short f2bf(float f) {
    unsigned u = __float_as_uint(f);
    u += 0x7fffu + ((u >> 16) & 1u);   // round-to-nearest-even
    return (unsigned short)(u >> 16);
}

__device__ __forceinline__ float bf2f(unsigned short u) {
    return __uint_as_float(((unsigned)u) << 16);
}

__device__ __forceinline__ float g_fn(float x) {
    return (x >= 0.f) ? (x + 0.5f) : 1.0f / (1.0f + __expf(-x));
}

// MFMA wrapper: fragments live as i16 vectors (clean ds_read_b128 codegen);
// bit_cast to the builtin's bf16 vector type is an IR-level no-op.
__device__ __forceinline__ f32x16 mfma32(s16x8 a, s16x8 b, f32x16 c) {
    return __builtin_amdgcn_mfma_f32_32x32x16_bf16(
        __builtin_bit_cast(bf16x8, a), __builtin_bit_cast(bf16x8, b), c, 0, 0, 0);
}

// async global->LDS, 16B per lane; hardware dest = wave-uniform base + lane*16
__device__ __forceinline__ void async_copy16(const void* gsrc, void* ldst) {
    __builtin_amdgcn_global_load_lds(
        reinterpret_cast<__attribute__((address_space(1))) unsigned int*>(
            reinterpret_cast<uintptr_t>(gsrc)),
        reinterpret_cast<__attribute__((address_space(3))) unsigned int*>(
            reinterpret_cast<uintptr_t>(ldst)),
        16, 0, 0);
}

// ---------------- fused cast kernel ----------------

__global__ void cast_all(const float* __restrict__ x,
                         const float* __restrict__ Wf,
                         const float* __restrict__ Wi,
                         const float* __restrict__ Wh,
                         unsigned short* __restrict__ xb,
                         unsigned short* __restrict__ Wb) {
    const int NX = MM * DD / 4;                 // 4194304 float4s of x
    int i = blockIdx.x * 256 + threadIdx.x;
    if (i < NX) {
        float4 v = reinterpret_cast<const float4*>(x)[i];
        ushort4 o;
        o.x = f2bf(v.x); o.y = f2bf(v.y); o.z = f2bf(v.z); o.w = f2bf(v.w);
        reinterpret_cast<ushort4*>(xb)[i] = o;
    } else {
        int j = i - NX;                         // 0 .. 786431
        if (j < 3 * 262144) {
            int which = j >> 18, k = j & 262143;
            const float* s = (which == 0) ? Wf : ((which == 1) ? Wi : Wh);
            float4 v = reinterpret_cast<const float4*>(s)[k];
            ushort4 o;
            o.x = f2bf(v.x); o.y = f2bf(v.y); o.z = f2bf(v.z); o.w = f2bf(v.w);
            reinterpret_cast<ushort4*>(Wb)[(which << 18) + k] = o;
        }
    }
}

// ---------------- fused 3-gate GEMM + gate math (v11) ----------------
// R7 analysis: LDS-read time (~1570 cyc/CU/K-tile) == MFMA time (~1550
// cyc/SIMD) but they ran SERIALLY (step 4218 cyc, MfmaUtil 42 = 1550/4218):
// twin barriers re-align all waves into simultaneous read-phase then
// simultaneous grind-phase, and ks1's reads are issue-order-trapped behind
// ks0's MFMA grind. v11 restructures the step for overlap (geometry
// unchanged from R7: 256m x 64h x 3g block, 4 waves, per-wave 128m x 32h,
// BK=32, 56 KiB LDS, 2 blocks/CU):
//  (1) ONE barrier per step: [vmcnt(0); s_barrier; ISSUE(t+1); COMPUTE(t)].
//      Safety: buf[(t+1)%2] last read in COMPUTE(t-1); arrival at bar(t)
//      implies those reads completed (MFMA issue is lgkm-gated) -> post-
//      barrier ISSUE cannot race. vmcnt(0) is ~free: tile-t loads were
//      issued a full step (~2000 cyc) earlier.
//  (2) reads hoisted ahead of grinds: ks0 (7) + ks1-A (4) issue before the
//      first MFMA cluster; ks1-B between clusters. Early-done waves grind
//      while late waves read -> LDS/MFMA phases pipeline across waves.
//  (3) s_setprio(1) around each 12-MFMA cluster (T5).
// Bank-conflict counter ~7.3M is the structural 4-pass minimum for b128
// row-fragment reads (m134 floor ~12 cyc) -- not actionable.
// A/B frag (32x32x16): row = lane&31, k-granule = ks*2 + (lane>>5).
// C/D: row = (reg&3)+8*(reg>>2)+4*(lane>>5), col = lane&31 [m74/m101].

#define ISSUE(NB) do {                                                        \
    _Pragma("unroll")                                                         \
    for (int j = 0; j < 4; ++j)                                               \
        async_copy16(gptrA[j], smem + (NB) * 16384 + loffA[j]);               \
    _Pragma("unroll")                                                         \
    for (int j = 0; j < 3; ++j)                                               \
        async_copy16(gptrB[j], smem + 32768 + (NB) * 12288 + loffB[j]);       \
    _Pragma("unroll")                                                         \
    for (int j = 0; j < 4; ++j) gptrA[j] += 32;                               \
    _Pragma("unroll")                                                         \
    for (int j = 0; j < 3; ++j) gptrB[j] += 32;                               \
} while (0)

#define COMPUTE(CB) do {                                                      \
    const char* Ab = smem + (CB) * 16384;                                     \
    const char* Bb = smem + 32768 + (CB) * 12288;                             \
    const int c1 = c0 ^ 32;                                                   \
    s16x8 a0 = *reinterpret_cast<const s16x8*>(Ab + arowb + c0);              \
    s16x8 a1 = *reinterpret_cast<const s16x8*>(Ab + arowb + 2048 + c0);       \
    s16x8 a2 = *reinterpret_cast<const s16x8*>(Ab + arowb + 4096 + c0);       \
    s16x8 a3 = *reinterpret_cast<const s16x8*>(Ab + arowb + 6144 + c0);       \
    s16x8 b0 = *reinterpret_cast<const s16x8*>(Bb + browb + c0);              \
    s16x8 b1 = *reinterpret_cast<const s16x8*>(Bb + browb + 4096 + c0);       \
    s16x8 b2 = *reinterpret_cast<const s16x8*>(Bb + browb + 8192 + c0);       \
    s16x8 A0 = *reinterpret_cast<const s16x8*>(Ab + arowb + c1);              \
    s16x8 A1 = *reinterpret_cast<const s16x8*>(Ab + arowb + 2048 + c1);       \
    s16x8 A2 = *reinterpret_cast<const s16x8*>(Ab + arowb + 4096 + c1);       \
    s16x8 A3 = *reinterpret_cast<const s16x8*>(Ab + arowb + 6144 + c1);       \
    __builtin_amdgcn_s_setprio(1);                                            \
    acc[0][0] = mfma32(a0, b0, acc[0][0]);                                    \
    acc[1][0] = mfma32(a0, b1, acc[1][0]);                                    \
    acc[2][0] = mfma32(a0, b2, acc[2][0]);                                    \
    acc[0][1] = mfma32(a1, b0, acc[0][1]);                                    \
    acc[1][1] = mfma32(a1, b1, acc[1][1]);                                    \
    acc[2][1] = mfma32(a1, b2, acc[2][1]);                                    \
    acc[0][2] = mfma32(a2, b0, acc[0][2]);                                    \
    acc[1][2] = mfma32(a2, b1, acc[1][2]);                                    \
    acc[2][2] = mfma32(a2, b2, acc[2][2]);                                    \
    acc[0][3] = mfma32(a3, b0, acc[0][3]);                                    \
    acc[1][3] = mfma32(a3, b1, acc[1][3]);                                    \
    acc[2][3] = mfma32(a3, b2, acc[2][3]);                                    \
    __builtin_amdgcn_s_setprio(0);                                            \
    s16x8 B0 = *reinterpret_cast<const s16x8*>(Bb + browb + c1);              \
    s16x8 B1 = *reinterpret_cast<const s16x8*>(Bb + browb + 4096 + c1);       \
    s16x8 B2 = *reinterpret_cast<const s16x8*>(Bb + browb + 8192 + c1);       \
    __builtin_amdgcn_s_setprio(1);                                            \
    acc[0][0] = mfma32(A0, B0, acc[0][0]);                                    \
    acc[1][0] = mfma32(A0, B1, acc[1][0]);                                    \
    acc[2][0] = mfma32(A0, B2, acc[2][0]);                                    \
    acc[0][1] = mfma32(A1, B0, acc[0][1]);                                    \
    acc[1][1] = mfma32(A1, B1, acc[1][1]);                                    \
    acc[2][1] = mfma32(A1, B2, acc[2][1]);                                    \
    acc[0][2] = mfma32(A2, B0, acc[0][2]);                                    \
    acc[1][2] = mfma32(A2, B1, acc[1][2]);                                    \
    acc[2][2] = mfma32(A2, B2, acc[2][2]);                                    \
    acc[0][3] = mfma32(A3, B0, acc[0][3]);                                    \
    acc[1][3] = mfma32(A3, B1, acc[1][3]);                                    \
    acc[2][3] = mfma32(A3, B2, acc[2][3]);                                    \
    __builtin_amdgcn_s_setprio(0);                                            \
} while (0)

#define STEP(CB, NB, DO_ISSUE) do {                                           \
    asm volatile("s_waitcnt vmcnt(0)" ::: "memory");                          \
    __builtin_amdgcn_s_barrier();                                             \
    asm volatile("" ::: "memory");                                            \
    if (DO_ISSUE) ISSUE(NB);                                                  \
    COMPUTE(CB);                                                              \
} while (0)

__global__ __launch_bounds__(256, 2) void gemm_gates(
    const unsigned short* __restrict__ xb,
    const unsigned short* __restrict__ Wb,
    const float* __restrict__ bf_p, const float* __restrict__ bi_p,
    const float* __restrict__ bh_p,
    unsigned short* __restrict__ F, unsigned short* __restrict__ V) {
    __shared__ char smem[57344];   // A0|A1 (32 KiB) + B0|B1 (24 KiB)

    const int tid  = threadIdx.x;
    const int wave = tid >> 6;          // 0..3
    const int lane = tid & 63;

    // XCD swizzle (bijective over 1024 blocks): blocks sharing bm land on
    // one XCD (A slice L2-resident); consecutive jj share bh (B slice).
    const int bi  = blockIdx.x;         // 0..1023
    const int xcd = bi & 7;
    const int jj  = bi >> 3;            // 0..127 per-XCD stream
    const int bm  = ((jj & 7) << 3) | xcd;    // [0,64)
    const int bh  = jj >> 3;                  // [0,16)

    const int pm   = wave >> 1;         // 0..1  (128-row m patch)
    const int ph   = wave & 1;          // 0..1  (32-col h patch)

    // ---- staging: one instr = 16 rows x 64 B. Lane -> local row lane>>2,
    // slot lane&3. Stored chunk at (row r, slot s_) = s_ ^ mask(r),
    // mask(r) = ((r>>1)&3) ^ ((r>>3)&3); r = s*16 + (lane>>2) ->
    // mask = ((lane>>3)&3) ^ ((s*2 + (lane>>5))&3).
    const unsigned short* gptrA[4];
    const unsigned short* gptrB[3];
    int loffA[4], loffB[3];
#pragma unroll
    for (int j = 0; j < 4; ++j) {
        int s = wave + j * 4;           // 0..15
        int gch = (lane & 3) ^ ((lane >> 3) & 3) ^ ((s * 2 + (lane >> 5)) & 3);
        int row = bm * 256 + s * 16 + (lane >> 2);
        gptrA[j] = xb + (size_t)row * DD + gch * 8;
        loffA[j] = s * 1024;
    }
#pragma unroll
    for (int j = 0; j < 3; ++j) {
        int s = wave + j * 4;           // 0..11: gate = s>>2, h-seg = s&3
        int gch = (lane & 3) ^ ((lane >> 3) & 3) ^ ((s * 2 + (lane >> 5)) & 3);
        int row = (s >> 2) * HH + bh * 64 + (s & 3) * 16 + (lane >> 2);
        gptrB[j] = Wb + (size_t)row * DD + gch * 8;
        loffB[j] = s * 1024;
    }

    // ---- compute-side lane constants (byte offsets) ----
    // frag row = base + (lane&31) (bases all mult. of 32 -> mask from lane
    // bits only); want granule 2ks + (lane>>5); slot = want ^ mask(row):
    const int c0 = (((lane >> 5) ^ ((lane >> 1) & 3) ^ ((lane >> 3) & 3)) << 4);
    const int arowb = (pm * 128 + (lane & 31)) * 64;  // mt -> +mt*2048
    const int browb = (ph * 32 + (lane & 31)) * 64;   // gate g -> +g*4096

    f32x16 acc[3][4];
#pragma unroll
    for (int g = 0; g < 3; ++g)
#pragma unroll
        for (int mt = 0; mt < 4; ++mt)
            acc[g][mt] = (f32x16)(0.f);

    ISSUE(0);                           // prologue: tile 0 -> buf 0
    for (int t = 0; t < 15; ++t) {      // kb = 0..29
        STEP(0, 1, 1);
        STEP(1, 0, 1);
    }
    STEP(0, 1, 1);                      // kb = 30, stages tile31 -> buf1
    STEP(1, 0, 0);                      // kb = 31, last (no issue)

    // epilogue: bias + normalized gates (exp form), write f and v (bf16)
    const int h   = bh * 64 + ph * 32 + (lane & 31);
    const float bfs = bf_p[h], bis = bi_p[h], bhs = bh_p[h];
    const int mb  = bm * 256 + pm * 128 + ((lane >> 5) << 2);
#pragma unroll
    for (int mt = 0; mt < 4; ++mt) {
#pragma unroll
        for (int r = 0; r < 16; ++r) {
            const int m = mb + mt * 32 + (r & 3) + ((r >> 2) << 3);
            float zf = acc[0][mt][r] + bfs;
            float zi = acc[1][mt][r] + bis;
            float zh = acc[2][mt][r] + bhs;
            // f = sigmoid(-d), iv = sigmoid(d), d = sp(-zf)-sp(-zi)
            //   = (1+eb)/(2+ea+eb), (1+ea)/(2+ea+eb); clamp avoids inf/inf
            float ea = __expf(fminf(-zf, 60.f));
            float eb = __expf(fminf(-zi, 60.f));
            float s  = __builtin_amdgcn_rcpf(2.f + ea + eb);
            float fv = (1.f + eb) * s;
            float iv = (1.f + ea) * s;
            float gg = (zh >= 0.f) ? (zh + 0.5f)
                                   : __builtin_amdgcn_rcpf(1.f + __expf(-zh));
            size_t o = (size_t)m * HH + h;
            F[o] = f2bf(fv);
            V[o] = f2bf(iv * gg);
        }
    }
}

// ---------------- scan (3-pass chunked linear scan) ----------------
// h_t = f_t*h_{t-1} + v_t ; f+i=1 convex combination -> stable in fp32.
// F/V in bf16, summaries and output fp32.

__global__ void scan1_kernel(const unsigned short* __restrict__ F,
                             const unsigned short* __restrict__ V,
                             float* __restrict__ Fc, float* __restrict__ Vc) {
    const int bx = blockIdx.x, tid = threadIdx.x;
    const int c = bx & (NC - 1), b = bx >> 7;
    const ushort4* F4 = (const ushort4*)F;
    const ushort4* V4 = (const ushort4*)V;
    size_t base = ((size_t)(b * TT + c * CL) * HH) / 4 + tid;
    float4 Fp = {1.f, 1.f, 1.f, 1.f}, hv = {0.f, 0.f, 0.f, 0.f};
#pragma unroll 8
    for (int s = 0; s < CL; ++s) {
        ushort4 fu = F4[base + (size_t)s * (HH / 4)];
        ushort4 vu = V4[base + (size_t)s * (HH / 4)];
        hv.x = fmaf(bf2f(fu.x), hv.x, bf2f(vu.x)); Fp.x *= bf2f(fu.x);
        hv.y = fmaf(bf2f(fu.y), hv.y, bf2f(vu.y)); Fp.y *= bf2f(fu.y);
        hv.z = fmaf(bf2f(fu.z), hv.z, bf2f(vu.z)); Fp.z *= bf2f(fu.z);
        hv.w = fmaf(bf2f(fu.w), hv.w, bf2f(vu.w)); Fp.w *= bf2f(fu.w);
    }
    size_t ci = ((size_t)(b * NC + c) * HH) / 4 + tid;
    ((float4*)Fc)[ci] = Fp;
    ((float4*)Vc)[ci] = hv;
}

__global__ void scan2_kernel(const float* __restrict__ h0,
                             const float* __restrict__ Fc,
                             const float* __restrict__ Vc,
                             float* __restrict__ Hin) {
    const int gid = blockIdx.x * 256 + threadIdx.x;   // 0..4095
    const int b = gid >> 10, h = gid & (HH - 1);
    float carry = g_fn(h0[gid]);
#pragma unroll 8
    for (int c = 0; c < NC; ++c) {
        int ci = (b * NC + c) * HH + h;
        Hin[ci] = carry;
        carry = fmaf(Fc[ci], carry, Vc[ci]);
    }
}

__global__ void scan3_kernel(const unsigned short* __restrict__ F,
                             const unsigned short* __restrict__ V,
                             const float* __restrict__ Hin,
                             float* __restrict__ Out) {
    const int bx = blockIdx.x, tid = threadIdx.x;
    const int c = bx & (NC - 1), b = bx >> 7;
    const ushort4* F4 = (const ushort4*)F;
    const ushort4* V4 = (const ushort4*)V;
    float4* O4 = (float4*)Out;
    size_t base = ((size_t)(b * TT + c * CL) * HH) / 4 + tid;
    size_t ci = ((size_t)(b * NC + c) * HH) / 4 + tid;
    float4 carry = ((const float4*)Hin)[ci];
#pragma unroll 8
    for (int s = 0; s < CL; ++s) {
        size_t idx = base + (size_t)s * (HH / 4);
        ushort4 fu = F4[idx];
        ushort4 vu = V4[idx];
        carry.x = fmaf(bf2f(fu.x), carry.x, bf2f(vu.x));
        carry.y = fmaf(bf2f(fu.y), carry.y, bf2f(vu.y));
        carry.z = fmaf(bf2f(fu.z), carry.z, bf2f(vu.z));
        carry.w = fmaf(bf2f(fu.w), carry.w, bf2f(vu.w));
        O4[idx] = carry;
    }
}

// ---------------- launch ----------------

extern "C" void kernel_launch(void* const* d_in, const int* in_sizes, int n_in,
                              void* d_out, int out_size, void* d_ws, size_t ws_size,
                              hipStream_t stream) {
    const float* x   = (const float*)d_in[0];
    const float* h0  = (const float*)d_in[1];
    const float* Wf  = (const float*)d_in[2];
    const float* bfp = (const float*)d_in[3];
    const float* Wi  = (const float*)d_in[4];
    const float* bip = (const float*)d_in[5];
    const float* Wh  = (const float*)d_in[6];
    const float* bhp = (const float*)d_in[7];
    float* out = (float*)d_out;

    char* ws = (char*)d_ws;
    unsigned short* xb = (unsigned short*)ws;                   // 32 MiB bf16 x
    unsigned short* Wb = (unsigned short*)(ws + 33554432);      // 6 MiB bf16 W
    unsigned short* Fb = (unsigned short*)(ws + 39845888);      // 32 MiB bf16 f
    unsigned short* Vb = (unsigned short*)(ws + 73400320);      // 32 MiB bf16 v
    float* Fc  = (float*)(ws);                                  // 2 MiB (aliases xb)
    float* Vc  = (float*)(ws + 2097152);                        // 2 MiB
    float* Hin = (float*)(ws + 4194304);                        // 2 MiB

    cast_all<<<19456, 256, 0, stream>>>(x, Wf, Wi, Wh, xb, Wb);
    gemm_gates<<<1024, 256, 0, stream>>>(xb, Wb, bfp, bip, bhp, Fb, Vb);
    scan1_kernel<<<BB * NC, 256, 0, stream>>>(Fb, Vb, Fc, Vc);
    scan2_kernel<<<16, 256, 0, stream>>>(h0, Fc, Vc, Hin);
    scan3_kernel<<<BB * NC, 256, 0, stream>>>(Fb, Vb, Hin, out);
}

// Round 9
// 285.737 us; speedup vs baseline: 2.1572x; 2.1572x over previous
//
#include <hip/hip_runtime.h>
#include <stdint.h>

// Problem constants (fixed shapes)
#define BB 4
#define TT 4096
#define DD 1024
#define HH 1024
#define MM (BB * TT)      // 16384
#define NC 128            // scan chunks
#define CL (TT / NC)      // 32 steps per chunk

typedef __bf16 bf16x8 __attribute__((ext_vector_type(8)));
typedef short  s16x8  __attribute__((ext_vector_type(8)));
typedef float  f32x4  __attribute__((ext_vector_type(4)));
typedef float  f32x16 __attribute__((ext_vector_type(16)));

// ---------------- helpers ----------------

__device__ __forceinline__ unsigned short f2bf(float f) {
    unsigned u = __float_as_uint(f);
    u += 0x7fffu + ((u >> 16) & 1u);   // round-to-nearest-even
    return (unsigned short)(u >> 16);
}

__device__ __forceinline__ float bf2f(unsigned short u) {
    return __uint_as_float(((unsigned)u) << 16);
}

__device__ __forceinline__ float g_fn(float x) {
    return (x >= 0.f) ? (x + 0.5f) : 1.0f / (1.0f + __expf(-x));
}

// MFMA wrapper: fragments live as i16 vectors (clean ds_read_b128 codegen);
// bit_cast to the builtin's bf16 vector type is an IR-level no-op.
__device__ __forceinline__ f32x16 mfma32(s16x8 a, s16x8 b, f32x16 c) {
    return __builtin_amdgcn_mfma_f32_32x32x16_bf16(
        __builtin_bit_cast(bf16x8, a), __builtin_bit_cast(bf16x8, b), c, 0, 0, 0);
}

// async global->LDS, 16B per lane; hardware dest = wave-uniform base + lane*16
__device__ __forceinline__ void async_copy16(const void* gsrc, void* ldst) {
    __builtin_amdgcn_global_load_lds(
        reinterpret_cast<__attribute__((address_space(1))) unsigned int*>(
            reinterpret_cast<uintptr_t>(gsrc)),
        reinterpret_cast<__attribute__((address_space(3))) unsigned int*>(
            reinterpret_cast<uintptr_t>(ldst)),
        16, 0, 0);
}

// ---------------- fused cast kernel ----------------

__global__ void cast_all(const float* __restrict__ x,
                         const float* __restrict__ Wf,
                         const float* __restrict__ Wi,
                         const float* __restrict__ Wh,
                         unsigned short* __restrict__ xb,
                         unsigned short* __restrict__ Wb) {
    const int NX = MM * DD / 4;                 // 4194304 float4s of x
    int i = blockIdx.x * 256 + threadIdx.x;
    if (i < NX) {
        float4 v = reinterpret_cast<const float4*>(x)[i];
        ushort4 o;
        o.x = f2bf(v.x); o.y = f2bf(v.y); o.z = f2bf(v.z); o.w = f2bf(v.w);
        reinterpret_cast<ushort4*>(xb)[i] = o;
    } else {
        int j = i - NX;                         // 0 .. 786431
        if (j < 3 * 262144) {
            int which = j >> 18, k = j & 262143;
            const float* s = (which == 0) ? Wf : ((which == 1) ? Wi : Wh);
            float4 v = reinterpret_cast<const float4*>(s)[k];
            ushort4 o;
            o.x = f2bf(v.x); o.y = f2bf(v.y); o.z = f2bf(v.z); o.w = f2bf(v.w);
            reinterpret_cast<ushort4*>(Wb)[(which << 18) + k] = o;
        }
    }
}

// ---------------- fused 3-gate GEMM + gate math (v12) ----------------
// R8 post-mortem: hoisted frags spilled acc to scratch (WRITE 65MB->1GB).
// R9 = R7 structure VERBATIM; single lever = register reduction to restore
// true 2-blocks/CU occupancy (R7 ran 320 unified regs/wave -> only ~6
// waves/CU, no block anti-phasing -> serial LDS/MFMA phases, MfmaUtil 42).
//  * Swizzle mask made j-invariant: M(r) = ((r>>1)&3) ^ ((r>>3)&1)
//    (row bits 1-3 only) -> ALL 7 staging instrs share ONE per-lane voff
//    (advanced by a single v_add per tile); 7 bases are wave-uniform
//    (readfirstlane) -> SGPR pairs. Saves ~13 VGPR.
//  * Read-side conflict class unchanged vs R7 (8 lanes per (l0,slot)
//    class, 2 distinct addrs -> same ~4 cyc/read penalty).
// Target: <=256 unified regs/wave -> 8 waves/CU -> blocks anti-phase and
// LDS-read phases overlap the other block's MFMA grind.
// Geometry (unchanged): 256m x 64h x 3g block, 4 waves (2pm x 2ph),
// per-wave 128m x 32h x 3g, BK=32, 56 KiB LDS dbuf, 1024 blocks.
// A/B frag (32x32x16): row = lane&31, k-granule = ks*2 + (lane>>5).
// C/D: row = (reg&3)+8*(reg>>2)+4*(lane>>5), col = lane&31 [m74/m101].

#define ISSUE(NB) do {                                                        \
    _Pragma("unroll")                                                         \
    for (int j = 0; j < 4; ++j)                                               \
        async_copy16(sbA[j] + voff, smem + (NB) * 16384 + ldsA[j]);           \
    _Pragma("unroll")                                                         \
    for (int j = 0; j < 3; ++j)                                               \
        async_copy16(sbB[j] + voff, smem + 32768 + (NB) * 12288 + ldsB[j]);   \
    voff += 32;                                                               \
} while (0)

#define COMPUTE(CB) do {                                                      \
    const char* Ab = smem + (CB) * 16384;                                     \
    const char* Bb = smem + 32768 + (CB) * 12288;                             \
    _Pragma("unroll")                                                         \
    for (int ks = 0; ks < 2; ++ks) {                                          \
        const int col = c0 ^ (ks << 5);                                       \
        s16x8 a0 = *reinterpret_cast<const s16x8*>(Ab + arowb + col);         \
        s16x8 a1 = *reinterpret_cast<const s16x8*>(Ab + arowb + 2048 + col);  \
        s16x8 a2 = *reinterpret_cast<const s16x8*>(Ab + arowb + 4096 + col);  \
        s16x8 a3 = *reinterpret_cast<const s16x8*>(Ab + arowb + 6144 + col);  \
        s16x8 b0 = *reinterpret_cast<const s16x8*>(Bb + browb + col);         \
        s16x8 b1 = *reinterpret_cast<const s16x8*>(Bb + browb + 4096 + col);  \
        s16x8 b2 = *reinterpret_cast<const s16x8*>(Bb + browb + 8192 + col);  \
        acc[0][0] = mfma32(a0, b0, acc[0][0]);                                \
        acc[1][0] = mfma32(a0, b1, acc[1][0]);                                \
        acc[2][0] = mfma32(a0, b2, acc[2][0]);                                \
        acc[0][1] = mfma32(a1, b0, acc[0][1]);                                \
        acc[1][1] = mfma32(a1, b1, acc[1][1]);                                \
        acc[2][1] = mfma32(a1, b2, acc[2][1]);                                \
        acc[0][2] = mfma32(a2, b0, acc[0][2]);                                \
        acc[1][2] = mfma32(a2, b1, acc[1][2]);                                \
        acc[2][2] = mfma32(a2, b2, acc[2][2]);                                \
        acc[0][3] = mfma32(a3, b0, acc[0][3]);                                \
        acc[1][3] = mfma32(a3, b1, acc[1][3]);                                \
        acc[2][3] = mfma32(a3, b2, acc[2][3]);                                \
    }                                                                         \
} while (0)

#define STEP(CB, NB, LAST) do {                                               \
    if (!(LAST)) {                                                            \
        ISSUE(NB);                                                            \
        asm volatile("s_waitcnt vmcnt(7)" ::: "memory");                      \
    } else {                                                                  \
        asm volatile("s_waitcnt vmcnt(0)" ::: "memory");                      \
    }                                                                         \
    __builtin_amdgcn_s_barrier();                                             \
    COMPUTE(CB);                                                              \
    asm volatile("s_waitcnt lgkmcnt(0)" ::: "memory");                        \
    __builtin_amdgcn_s_barrier();                                             \
} while (0)

__global__ __launch_bounds__(256, 2) void gemm_gates(
    const unsigned short* __restrict__ xb,
    const unsigned short* __restrict__ Wb,
    const float* __restrict__ bf_p, const float* __restrict__ bi_p,
    const float* __restrict__ bh_p,
    unsigned short* __restrict__ F, unsigned short* __restrict__ V) {
    __shared__ char smem[57344];   // A0|A1 (32 KiB) + B0|B1 (24 KiB)

    const int tid  = threadIdx.x;
    const int lane = tid & 63;
    // wave index forced scalar so staging bases land in SGPRs.
    const int wub  = __builtin_amdgcn_readfirstlane(tid >> 6);   // 0..3

    // XCD swizzle (bijective over 1024 blocks): blocks sharing bm land on
    // one XCD (A slice L2-resident); consecutive jj share bh (B slice).
    const int bi  = blockIdx.x;         // 0..1023
    const int xcd = bi & 7;
    const int jj  = bi >> 3;            // 0..127 per-XCD stream
    const int bm  = ((jj & 7) << 3) | xcd;    // [0,64)
    const int bh  = jj >> 3;                  // [0,16)

    const int pm   = wub >> 1;          // 0..1  (128-row m patch)
    const int ph   = wub & 1;           // 0..1  (32-col h patch)

    // ---- staging: one instr = 16 rows x 64 B. Lane -> local row lane>>2,
    // slot lane&3. Stored chunk at (row r, slot s_) = s_ ^ M(r),
    // M(r) = ((r>>1)&3) ^ ((r>>3)&1)  [row bits 1-3 only -> j-invariant].
    // Per-lane: r bits = lr = lane>>2 -> fetch chunk
    //   gch = (lane&3) ^ ((lane>>3)&3) ^ ((lane>>5)&1).
    // ONE shared per-lane offset (elements), advanced 32/tile:
    int voff = (lane >> 2) * DD +
               (((lane & 3) ^ ((lane >> 3) & 3) ^ ((lane >> 5) & 1)) << 3);

    // wave-uniform staging bases (SGPR) and LDS slice offsets
    const unsigned short* sbA[4];
    const unsigned short* sbB[3];
    int ldsA[4], ldsB[3];
#pragma unroll
    for (int j = 0; j < 4; ++j) {
        int s = wub + j * 4;            // 0..15
        sbA[j]  = xb + (size_t)(bm * 256 + s * 16) * DD;
        ldsA[j] = s * 1024;
    }
#pragma unroll
    for (int j = 0; j < 3; ++j) {
        int s = wub + j * 4;            // 0..11: gate = s>>2, h-seg = s&3
        sbB[j]  = Wb + (size_t)((s >> 2) * HH + bh * 64 + (s & 3) * 16) * DD;
        ldsB[j] = s * 1024;
    }

    // ---- compute-side lane constants (byte offsets) ----
    // frag row = base + (lane&31), bases mult. of 32 -> M from lane bits:
    // M = ((lane>>1)&3) ^ ((lane>>3)&1); want granule = 2ks + (lane>>5);
    // slot = want ^ M; ks toggles bit1 -> col_ks1 = col_ks0 ^ 32.
    const int c0 = ((((lane >> 5) & 1) ^ ((lane >> 1) & 3) ^ ((lane >> 3) & 1)) << 4);
    const int arowb = (pm * 128 + (lane & 31)) * 64;  // mt -> +mt*2048
    const int browb = (ph * 32 + (lane & 31)) * 64;   // gate g -> +g*4096

    f32x16 acc[3][4];
#pragma unroll
    for (int g = 0; g < 3; ++g)
#pragma unroll
        for (int mt = 0; mt < 4; ++mt)
            acc[g][mt] = (f32x16)(0.f);

    ISSUE(0);                           // prologue: tile 0 -> buf 0
    for (int t = 0; t < 15; ++t) {      // kb = 0..29
        STEP(0, 1, 0);
        STEP(1, 0, 0);
    }
    STEP(0, 1, 0);                      // kb = 30, prefetch tile31 -> buf1
    STEP(1, 0, 1);                      // kb = 31, last

    // epilogue: bias + normalized gates (exp form), write f and v (bf16)
    const int h   = bh * 64 + ph * 32 + (lane & 31);
    const float bfs = bf_p[h], bis = bi_p[h], bhs = bh_p[h];
    const int mb  = bm * 256 + pm * 128 + ((lane >> 5) << 2);
#pragma unroll
    for (int mt = 0; mt < 4; ++mt) {
#pragma unroll
        for (int r = 0; r < 16; ++r) {
            const int m = mb + mt * 32 + (r & 3) + ((r >> 2) << 3);
            float zf = acc[0][mt][r] + bfs;
            float zi = acc[1][mt][r] + bis;
            float zh = acc[2][mt][r] + bhs;
            // f = sigmoid(-d), iv = sigmoid(d), d = sp(-zf)-sp(-zi)
            //   = (1+eb)/(2+ea+eb), (1+ea)/(2+ea+eb); clamp avoids inf/inf
            float ea = __expf(fminf(-zf, 60.f));
            float eb = __expf(fminf(-zi, 60.f));
            float s  = __builtin_amdgcn_rcpf(2.f + ea + eb);
            float fv = (1.f + eb) * s;
            float iv = (1.f + ea) * s;
            float gg = (zh >= 0.f) ? (zh + 0.5f)
                                   : __builtin_amdgcn_rcpf(1.f + __expf(-zh));
            size_t o = (size_t)m * HH + h;
            F[o] = f2bf(fv);
            V[o] = f2bf(iv * gg);
        }
    }
}

// ---------------- scan (3-pass chunked linear scan) ----------------
// h_t = f_t*h_{t-1} + v_t ; f+i=1 convex combination -> stable in fp32.
// F/V in bf16, summaries and output fp32.

__global__ void scan1_kernel(const unsigned short* __restrict__ F,
                             const unsigned short* __restrict__ V,
                             float* __restrict__ Fc, float* __restrict__ Vc) {
    const int bx = blockIdx.x, tid = threadIdx.x;
    const int c = bx & (NC - 1), b = bx >> 7;
    const ushort4* F4 = (const ushort4*)F;
    const ushort4* V4 = (const ushort4*)V;
    size_t base = ((size_t)(b * TT + c * CL) * HH) / 4 + tid;
    float4 Fp = {1.f, 1.f, 1.f, 1.f}, hv = {0.f, 0.f, 0.f, 0.f};
#pragma unroll 8
    for (int s = 0; s < CL; ++s) {
        ushort4 fu = F4[base + (size_t)s * (HH / 4)];
        ushort4 vu = V4[base + (size_t)s * (HH / 4)];
        hv.x = fmaf(bf2f(fu.x), hv.x, bf2f(vu.x)); Fp.x *= bf2f(fu.x);
        hv.y = fmaf(bf2f(fu.y), hv.y, bf2f(vu.y)); Fp.y *= bf2f(fu.y);
        hv.z = fmaf(bf2f(fu.z), hv.z, bf2f(vu.z)); Fp.z *= bf2f(fu.z);
        hv.w = fmaf(bf2f(fu.w), hv.w, bf2f(vu.w)); Fp.w *= bf2f(fu.w);
    }
    size_t ci = ((size_t)(b * NC + c) * HH) / 4 + tid;
    ((float4*)Fc)[ci] = Fp;
    ((float4*)Vc)[ci] = hv;
}

__global__ void scan2_kernel(const float* __restrict__ h0,
                             const float* __restrict__ Fc,
                             const float* __restrict__ Vc,
                             float* __restrict__ Hin) {
    const int gid = blockIdx.x * 256 + threadIdx.x;   // 0..4095
    const int b = gid >> 10, h = gid & (HH - 1);
    float carry = g_fn(h0[gid]);
#pragma unroll 8
    for (int c = 0; c < NC; ++c) {
        int ci = (b * NC + c) * HH + h;
        Hin[ci] = carry;
        carry = fmaf(Fc[ci], carry, Vc[ci]);
    }
}

__global__ void scan3_kernel(const unsigned short* __restrict__ F,
                             const unsigned short* __restrict__ V,
                             const float* __restrict__ Hin,
                             float* __restrict__ Out) {
    const int bx = blockIdx.x, tid = threadIdx.x;
    const int c = bx & (NC - 1), b = bx >> 7;
    const ushort4* F4 = (const ushort4*)F;
    const ushort4* V4 = (const ushort4*)V;
    float4* O4 = (float4*)Out;
    size_t base = ((size_t)(b * TT + c * CL) * HH) / 4 + tid;
    size_t ci = ((size_t)(b * NC + c) * HH) / 4 + tid;
    float4 carry = ((const float4*)Hin)[ci];
#pragma unroll 8
    for (int s = 0; s < CL; ++s) {
        size_t idx = base + (size_t)s * (HH / 4);
        ushort4 fu = F4[idx];
        ushort4 vu = V4[idx];
        carry.x = fmaf(bf2f(fu.x), carry.x, bf2f(vu.x));
        carry.y = fmaf(bf2f(fu.y), carry.y, bf2f(vu.y));
        carry.z = fmaf(bf2f(fu.z), carry.z, bf2f(vu.z));
        carry.w = fmaf(bf2f(fu.w), carry.w, bf2f(vu.w));
        O4[idx] = carry;
    }
}

// ---------------- launch ----------------

extern "C" void kernel_launch(void* const* d_in, const int* in_sizes, int n_in,
                              void* d_out, int out_size, void* d_ws, size_t ws_size,
                              hipStream_t stream) {
    const float* x   = (const float*)d_in[0];
    const float* h0  = (const float*)d_in[1];
    const float* Wf  = (const float*)d_in[2];
    const float* bfp = (const float*)d_in[3];
    const float* Wi  = (const float*)d_in[4];
    const float* bip = (const float*)d_in[5];
    const float* Wh  = (const float*)d_in[6];
    const float* bhp = (const float*)d_in[7];
    float* out = (float*)d_out;

    char* ws = (char*)d_ws;
    unsigned short* xb = (unsigned short*)ws;                   // 32 MiB bf16 x
    unsigned short* Wb = (unsigned short*)(ws + 33554432);      // 6 MiB bf16 W
    unsigned short* Fb = (unsigned short*)(ws + 39845888);      // 32 MiB bf16 f
    unsigned short* Vb = (unsigned short*)(ws + 73400320);      // 32 MiB bf16 v
    float* Fc  = (float*)(ws);                                  // 2 MiB (aliases xb)
    float* Vc  = (float*)(ws + 2097152);                        // 2 MiB
    float* Hin = (float*)(ws + 4194304);                        // 2 MiB

    cast_all<<<19456, 256, 0, stream>>>(x, Wf, Wi, Wh, xb, Wb);
    gemm_gates<<<1024, 256, 0, stream>>>(xb, Wb, bfp, bip, bhp, Fb, Vb);
    scan1_kernel<<<BB * NC, 256, 0, stream>>>(Fb, Vb, Fc, Vc);
    scan2_kernel<<<16, 256, 0, stream>>>(h0, Fc, Vc, Hin);
    scan3_kernel<<<BB * NC, 256, 0, stream>>>(Fb, Vb, Hin, out);
}